// Round 1
// baseline (1410.418 us; speedup 1.0000x reference)
//
#include <hip/hip_runtime.h>
#include <math.h>

#define NB   8
#define NC   192
#define NPIX 3136
#define NBLK 49            // 3136/64
#define GRID_LL (NB*NBLK)  // 392
#define FINF 3.4e38f

__device__ __forceinline__ float gelu_f(float x){
    // jax.nn.gelu approximate=True (tanh form)
    float u = 0.7978845608028654f * (x + 0.044715f * x * x * x);
    return 0.5f * x * (1.0f + tanhf(u));
}

// insert candidate into sorted-ascending (d, id) 9-list; lex tie-break on lower idx
__device__ __forceinline__ void ins9(float (&d)[9], int (&id)[9], float nd, int ni){
    bool better = (nd < d[8]) || (nd == d[8] && ni < id[8]);
    if (better){
        d[8] = nd; id[8] = ni;
        #pragma unroll
        for (int s = 8; s > 0; --s){
            bool sw = (d[s] < d[s-1]) || (d[s] == d[s-1] && id[s] < id[s-1]);
            if (sw){
                float td = d[s]; d[s] = d[s-1]; d[s-1] = td;
                int   ti = id[s]; id[s] = id[s-1]; id[s-1] = ti;
            }
        }
    }
}

// ---------------------------------------------------------------------------
// Fused GEMM + lorentz_linear.
// out_row = lorentz(gelu(in_row) @ W^T + b) [+ x_transposed] [+ rowmajor res]
// Block: 256 thr = 16 tx (12 cols each) x 16 ty (4 rows each). Tile 64 x 192.
// ---------------------------------------------------------------------------
template<int K, bool IN_X, bool ADD_X, bool ADD_RM, bool OUT_T>
__global__ __launch_bounds__(256, 4) void ll_kernel(
    const float* __restrict__ Ain, int in_stride,
    const float* __restrict__ Wt,     // [NC, K] row-major
    const float* __restrict__ bias,   // [NC]
    const float* __restrict__ sptr,   // scalar log_scale
    const float* __restrict__ Xres,   // x (B,C,N) residual, if ADD_X
    const float* __restrict__ Rrm, int r_stride,  // row-major residual, if ADD_RM
    float* __restrict__ Out, int out_stride)
{
    __shared__ float lA[32*68];    // [kk][mm], pad 68
    __shared__ float lW[32*196];   // [kk][nn], pad 196

    const int tid = threadIdx.x;
    const int tx = tid & 15, ty = tid >> 4;
    const int bid = blockIdx.x;
    const int b  = bid / NBLK;
    const int n0 = (bid % NBLK) * 64;
    const int row0 = b * NPIX + n0;

    float acc[4][12];
    #pragma unroll
    for (int mi = 0; mi < 4; ++mi)
        #pragma unroll
        for (int j = 0; j < 12; ++j) acc[mi][j] = 0.f;

    for (int kt = 0; kt < K/32; ++kt){
        // ---- stage A (gelu applied here) ----
        if (IN_X){
            #pragma unroll
            for (int r = 0; r < 2; ++r){
                int e  = tid + r*256;          // 512 float4 = 32k x 64m
                int kk = e >> 4;
                int m4 = (e & 15) * 4;
                float4 v = *(const float4*)&Ain[(b*NC + kt*32 + kk)*NPIX + n0 + m4];
                v.x = gelu_f(v.x); v.y = gelu_f(v.y); v.z = gelu_f(v.z); v.w = gelu_f(v.w);
                *(float4*)&lA[kk*68 + m4] = v;
            }
        } else {
            #pragma unroll
            for (int r = 0; r < 2; ++r){
                int e  = tid + r*256;
                int mm = e >> 3;
                int k4 = (e & 7) * 4;
                float4 v = *(const float4*)&Ain[(row0 + mm)*in_stride + kt*32 + k4];
                v.x = gelu_f(v.x); v.y = gelu_f(v.y); v.z = gelu_f(v.z); v.w = gelu_f(v.w);
                lA[(k4+0)*68 + mm] = v.x; lA[(k4+1)*68 + mm] = v.y;
                lA[(k4+2)*68 + mm] = v.z; lA[(k4+3)*68 + mm] = v.w;
            }
        }
        // ---- stage W (transposed) ----
        #pragma unroll
        for (int r = 0; r < 6; ++r){
            int e  = tid + r*256;              // 1536 float4 = 32k x 192n
            int nn = e >> 3;
            int k4 = (e & 7) * 4;
            float4 v = *(const float4*)&Wt[nn*K + kt*32 + k4];
            lW[(k4+0)*196 + nn] = v.x; lW[(k4+1)*196 + nn] = v.y;
            lW[(k4+2)*196 + nn] = v.z; lW[(k4+3)*196 + nn] = v.w;
        }
        __syncthreads();
        #pragma unroll
        for (int kk = 0; kk < 32; ++kk){
            float4 av = *(const float4*)&lA[kk*68 + ty*4];
            float4 w0 = *(const float4*)&lW[kk*196 + tx*12];
            float4 w1 = *(const float4*)&lW[kk*196 + tx*12 + 4];
            float4 w2 = *(const float4*)&lW[kk*196 + tx*12 + 8];
            float aw[4]  = {av.x, av.y, av.z, av.w};
            float wv[12] = {w0.x,w0.y,w0.z,w0.w, w1.x,w1.y,w1.z,w1.w, w2.x,w2.y,w2.z,w2.w};
            #pragma unroll
            for (int mi = 0; mi < 4; ++mi)
                #pragma unroll
                for (int j = 0; j < 12; ++j)
                    acc[mi][j] = fmaf(aw[mi], wv[j], acc[mi][j]);
        }
        __syncthreads();
    }

    // ---- lorentz epilogue ----
    const int lane = tid & 63;
    float es = expf(sptr[0]);
    float bv[12];
    #pragma unroll
    for (int q = 0; q < 3; ++q){
        float4 t4 = *(const float4*)&bias[tx*12 + q*4];
        bv[q*4+0] = t4.x; bv[q*4+1] = t4.y; bv[q*4+2] = t4.z; bv[q*4+3] = t4.w;
    }
    #pragma unroll
    for (int mi = 0; mi < 4; ++mi){
        float part = 0.f;
        #pragma unroll
        for (int j = 0; j < 12; ++j){
            float y = acc[mi][j] + bv[j];
            acc[mi][j] = y;
            if (!(tx == 0 && j == 0)) part += y * y;   // exclude global col 0
        }
        #pragma unroll
        for (int m = 1; m < 16; m <<= 1) part += __shfl_xor(part, m, 64);
        float y0   = __shfl(acc[mi][0], lane & 48, 64);   // col-0 value of this row
        float tval = es / (1.f + expf(-y0)) + 1.1f;
        float denom = fmaxf(part, 1e-8f);
        float sca  = (tval*tval - 1.f) / denom;
        float sqs  = sqrtf(sca);
        #pragma unroll
        for (int j = 0; j < 12; ++j){
            float o = acc[mi][j] * sqs;
            if (tx == 0 && j == 0) o = tval;
            acc[mi][j] = o;
        }
    }
    if (ADD_X){
        #pragma unroll
        for (int j = 0; j < 12; ++j){
            int c = tx*12 + j;
            float4 xv = *(const float4*)&Xres[(b*NC + c)*NPIX + n0 + ty*4];
            acc[0][j] += xv.x; acc[1][j] += xv.y; acc[2][j] += xv.z; acc[3][j] += xv.w;
        }
    }
    if (ADD_RM){
        #pragma unroll
        for (int mi = 0; mi < 4; ++mi){
            #pragma unroll
            for (int q = 0; q < 3; ++q){
                float4 rv = *(const float4*)&Rrm[(row0 + ty*4 + mi)*r_stride + tx*12 + q*4];
                acc[mi][q*4+0] += rv.x; acc[mi][q*4+1] += rv.y;
                acc[mi][q*4+2] += rv.z; acc[mi][q*4+3] += rv.w;
            }
        }
    }
    if (OUT_T){
        #pragma unroll
        for (int j = 0; j < 12; ++j){
            int c = tx*12 + j;
            float4 o = make_float4(acc[0][j], acc[1][j], acc[2][j], acc[3][j]);
            *(float4*)&Out[(b*NC + c)*NPIX + n0 + ty*4] = o;
        }
    } else {
        #pragma unroll
        for (int mi = 0; mi < 4; ++mi){
            #pragma unroll
            for (int q = 0; q < 3; ++q){
                float4 o = make_float4(acc[mi][q*4+0], acc[mi][q*4+1], acc[mi][q*4+2], acc[mi][q*4+3]);
                *(float4*)&Out[(row0 + ty*4 + mi)*out_stride + tx*12 + q*4] = o;
            }
        }
    }
}

// ---------------------------------------------------------------------------
// Row squared-norms of xn1 (stored in H cols [0,192), stride 384)
// ---------------------------------------------------------------------------
__global__ __launch_bounds__(256) void sq_kernel(const float* __restrict__ H, float* __restrict__ SQ){
    int tid = threadIdx.x;
    int row = blockIdx.x * 64 + (tid >> 2);
    const float* p = H + row*384 + (tid & 3)*48;
    float s = 0.f;
    #pragma unroll
    for (int q = 0; q < 12; ++q){
        float4 v = *(const float4*)&p[q*4];
        s = fmaf(v.x, v.x, fmaf(v.y, v.y, fmaf(v.z, v.z, fmaf(v.w, v.w, s))));
    }
    s += __shfl_xor(s, 1, 64);
    s += __shfl_xor(s, 2, 64);
    if ((tid & 3) == 0) SQ[row] = s;
}

// XOR-swizzled LDS address (chunk row stride 100 floats; swizzle quad bits by row>>2)
__device__ __forceinline__ int swz(int row, int c){
    return row*100 + (c ^ (((row >> 2) & 7) << 2));
}

// ---------------------------------------------------------------------------
// Fused kNN(top-9) + max-message. 64 i-rows per block, j in tiles of 64,
// c chunked x96. d' = sq_j - 2*dot (row-constant shift of reference d).
// ---------------------------------------------------------------------------
__global__ __launch_bounds__(256, 2) void knn_msg_kernel(
    const float* __restrict__ H, const float* __restrict__ SQ, float* __restrict__ Hout)
{
    __shared__ float lXi[6400];
    __shared__ float lXj[6400];
    __shared__ float lSq[64];
    __shared__ int   fidx[64*9];

    const int tid = threadIdx.x;
    const int tx = tid & 15, ty = tid >> 4;
    const int bid = blockIdx.x;
    const int b  = bid / NBLK;
    const int i0 = (bid % NBLK) * 64;
    const int base = b * NPIX;

    float topd[4][9]; int topi[4][9];
    #pragma unroll
    for (int mi = 0; mi < 4; ++mi)
        #pragma unroll
        for (int e = 0; e < 9; ++e){ topd[mi][e] = FINF; topi[mi][e] = 0x7FFFFFFF; }

    for (int jt = 0; jt < NBLK; ++jt){
        int j0 = jt * 64;
        float dac[4][4];
        #pragma unroll
        for (int mi = 0; mi < 4; ++mi)
            #pragma unroll
            for (int jj = 0; jj < 4; ++jj) dac[mi][jj] = 0.f;

        for (int ch = 0; ch < 2; ++ch){
            __syncthreads();
            #pragma unroll
            for (int r = 0; r < 6; ++r){
                int e  = tid + r*256;          // 1536 float4 = 64 rows x 24 quads
                int rw = e / 24;
                int c4 = (e - rw*24) * 4;
                float4 v = *(const float4*)&H[(base + i0 + rw)*384 + ch*96 + c4];
                *(float4*)&lXi[swz(rw, c4)] = v;
                float4 u = *(const float4*)&H[(base + j0 + rw)*384 + ch*96 + c4];
                *(float4*)&lXj[swz(rw, c4)] = u;
            }
            if (ch == 0 && tid < 16){
                float4 sv = *(const float4*)&SQ[base + j0 + tid*4];
                *(float4*)&lSq[tid*4] = sv;
            }
            __syncthreads();
            #pragma unroll
            for (int cq = 0; cq < 24; ++cq){
                float4 av[4]; float4 bw[4];
                #pragma unroll
                for (int mi = 0; mi < 4; ++mi) av[mi] = *(const float4*)&lXi[swz(ty*4+mi, cq*4)];
                #pragma unroll
                for (int jj = 0; jj < 4; ++jj) bw[jj] = *(const float4*)&lXj[swz(tx*4+jj, cq*4)];
                #pragma unroll
                for (int mi = 0; mi < 4; ++mi)
                    #pragma unroll
                    for (int jj = 0; jj < 4; ++jj){
                        float4 a = av[mi], c = bw[jj];
                        dac[mi][jj] = fmaf(a.x, c.x, fmaf(a.y, c.y, fmaf(a.z, c.z, fmaf(a.w, c.w, dac[mi][jj]))));
                    }
            }
        }
        #pragma unroll
        for (int jj = 0; jj < 4; ++jj){
            int j = j0 + tx*4 + jj;
            float sqj = lSq[tx*4 + jj];
            #pragma unroll
            for (int mi = 0; mi < 4; ++mi){
                float d = fmaf(-2.f, dac[mi][jj], sqj);
                ins9(topd[mi], topi[mi], d, j);
            }
        }
    }

    // ---- merge 16 tx-stripes per row (two halves reuse lXi/lXj as scratch) ----
    float* smd = lXi;
    int*   smi = (int*)lXj;
    for (int half = 0; half < 2; ++half){
        __syncthreads();
        if ((ty >> 3) == half){
            int tyl = ty & 7;
            #pragma unroll
            for (int mi = 0; mi < 4; ++mi){
                int rl = tyl*4 + mi;
                #pragma unroll
                for (int e = 0; e < 9; ++e){
                    smd[(rl*16 + tx)*9 + e] = topd[mi][e];
                    smi[(rl*16 + tx)*9 + e] = topi[mi][e];
                }
            }
        }
        __syncthreads();
        if (tid < 32){
            float md[9]; int mid[9];
            #pragma unroll
            for (int e = 0; e < 9; ++e){ md[e] = FINF; mid[e] = 0x7FFFFFFF; }
            for (int t = 0; t < 16; ++t){
                #pragma unroll
                for (int e = 0; e < 9; ++e)
                    ins9(md, mid, smd[(tid*16 + t)*9 + e], smi[(tid*16 + t)*9 + e]);
            }
            #pragma unroll
            for (int e = 0; e < 9; ++e) fidx[(half*32 + tid)*9 + e] = mid[e];
        }
    }
    __syncthreads();

    // ---- message: msg[i,c] = max_j xn1[j,c] - xn1[i,c]; write to H cols [192,384) ----
    {
        int row  = tid >> 2;
        int part = tid & 3;
        int i = i0 + row;
        int nbr[9];
        #pragma unroll
        for (int e = 0; e < 9; ++e) nbr[e] = fidx[row*9 + e];
        const float* pi = H + (base + i)*384 + part*48;
        float* po = Hout + (base + i)*384 + 192 + part*48;
        #pragma unroll
        for (int q = 0; q < 12; ++q){
            float4 mv = make_float4(-FINF, -FINF, -FINF, -FINF);
            #pragma unroll
            for (int e = 0; e < 9; ++e){
                float4 v = *(const float4*)&H[(base + nbr[e])*384 + part*48 + q*4];
                mv.x = fmaxf(mv.x, v.x); mv.y = fmaxf(mv.y, v.y);
                mv.z = fmaxf(mv.z, v.z); mv.w = fmaxf(mv.w, v.w);
            }
            float4 xi = *(const float4*)&pi[q*4];
            *(float4*)&po[q*4] = make_float4(mv.x - xi.x, mv.y - xi.y, mv.z - xi.z, mv.w - xi.w);
        }
    }
}

extern "C" void kernel_launch(void* const* d_in, const int* in_sizes, int n_in,
                              void* d_out, int out_size, void* d_ws, size_t ws_size,
                              hipStream_t stream)
{
    const float* x  = (const float*)d_in[0];
    const float* W1 = (const float*)d_in[1];
    const float* b1 = (const float*)d_in[2];
    const float* s1 = (const float*)d_in[3];
    const float* W2 = (const float*)d_in[4];
    const float* b2 = (const float*)d_in[5];
    const float* s2 = (const float*)d_in[6];
    const float* Wg = (const float*)d_in[7];
    const float* bg = (const float*)d_in[8];
    const float* sg = (const float*)d_in[9];
    const float* W3 = (const float*)d_in[10];
    const float* b3 = (const float*)d_in[11];
    const float* s3 = (const float*)d_in[12];
    const float* W4 = (const float*)d_in[13];
    const float* b4 = (const float*)d_in[14];
    const float* s4 = (const float*)d_in[15];

    float* H  = (float*)d_ws;                       // [25088][384]: xn1 | msg
    float* T1 = H  + (size_t)25088*384;             // LL1 out / reused as LL3 out
    float* X2 = T1 + (size_t)25088*192;             // graph-conv out (xn2)
    float* SQ = X2 + (size_t)25088*192;             // row sq-norms
    float* out = (float*)d_out;

    // ffn_lorentz #1
    ll_kernel<192, true , false, false, false><<<GRID_LL, 256, 0, stream>>>(x, 0,   W1, b1, s1, nullptr, nullptr, 0, T1, 192);
    ll_kernel<192, false, true , false, false><<<GRID_LL, 256, 0, stream>>>(T1, 192, W2, b2, s2, x,      nullptr, 0, H, 384);
    // graph conv
    sq_kernel<<<GRID_LL, 256, 0, stream>>>(H, SQ);
    knn_msg_kernel<<<GRID_LL, 256, 0, stream>>>(H, SQ, H);
    ll_kernel<384, false, false, false, false><<<GRID_LL, 256, 0, stream>>>(H, 384,  Wg, bg, sg, nullptr, nullptr, 0, X2, 192);
    // ffn_lorentz #2 + final shortcut, transposed store
    ll_kernel<192, false, false, false, false><<<GRID_LL, 256, 0, stream>>>(X2, 192, W3, b3, s3, nullptr, nullptr, 0, T1, 192);
    ll_kernel<192, false, true , true , true ><<<GRID_LL, 256, 0, stream>>>(T1, 192, W4, b4, s4, x,      X2, 192, out, 0);
}